// Round 1
// baseline (558.476 us; speedup 1.0000x reference)
//
#include <hip/hip_runtime.h>
#include <hip/hip_bf16.h>

// MoE top-1 (GShard) for MI355X.
// S=8192 tokens, m=1024, E=8, ffn=4096, C=1024.
// Pipeline: gate -> scan(loc) -> convert/transpose W1 -> gather Xd(bf16)
//        -> GEMM1(bf16 MFMA, relu) -> convert/transpose W2 (aliases W1T)
//        -> memset(out) -> GEMM2(bf16 MFMA, gate-scale + scatter).

#define NTOK 8192
#define DM   1024
#define NE   8
#define NF   4096
#define CAP  1024

typedef __bf16 bf16x8 __attribute__((ext_vector_type(8)));
typedef float  f32x4  __attribute__((ext_vector_type(4)));

__device__ __forceinline__ unsigned short f2bf(float f) {
    union { float f; unsigned int u; } v; v.f = f;
    unsigned int u = v.u;
    return (unsigned short)((u + 0x7FFFu + ((u >> 16) & 1u)) >> 16); // RNE
}

__device__ __forceinline__ void async_cp16(const unsigned short* g, unsigned short* l) {
    __builtin_amdgcn_global_load_lds(
        (const __attribute__((address_space(1))) void*)g,
        (__attribute__((address_space(3))) void*)l, 16, 0, 0);
}

// ---------------- gating: one wave per token ----------------
__global__ __launch_bounds__(256) void gate_kernel(
    const float* __restrict__ x, const float* __restrict__ wg,
    int* __restrict__ eid, float* __restrict__ gatev)
{
    int wave = threadIdx.x >> 6;
    int lane = threadIdx.x & 63;
    int t = blockIdx.x * 4 + wave;
    const float* xr = x + (size_t)t * DM;
    float acc[NE];
#pragma unroll
    for (int e = 0; e < NE; ++e) acc[e] = 0.f;
    for (int k = lane; k < DM; k += 64) {
        float xv = xr[k];
        const float4* wr = (const float4*)(wg + k * NE);
        float4 w0 = wr[0], w1 = wr[1];
        acc[0] += xv * w0.x; acc[1] += xv * w0.y;
        acc[2] += xv * w0.z; acc[3] += xv * w0.w;
        acc[4] += xv * w1.x; acc[5] += xv * w1.y;
        acc[6] += xv * w1.z; acc[7] += xv * w1.w;
    }
#pragma unroll
    for (int off = 32; off >= 1; off >>= 1) {
#pragma unroll
        for (int e = 0; e < NE; ++e) acc[e] += __shfl_xor(acc[e], off, 64);
    }
    if (lane == 0) {
        int best = 0; float bm = acc[0];
#pragma unroll
        for (int e = 1; e < NE; ++e) if (acc[e] > bm) { bm = acc[e]; best = e; } // first-max like jnp.argmax
        float ssum = 0.f;
#pragma unroll
        for (int e = 0; e < NE; ++e) ssum += __expf(acc[e] - bm);
        eid[t] = best;
        gatev[t] = 1.0f / ssum;  // softmax prob of argmax expert
    }
}

// ---------------- ordered per-expert cumsum (single block) ----------------
__global__ __launch_bounds__(1024) void scan_kernel(
    const int* __restrict__ eid, int* __restrict__ slot_token)
{
    __shared__ int sc[1024][NE];
    int tid = threadIdx.x;
#pragma unroll
    for (int i = 0; i < 8; ++i) slot_token[tid + i * 1024] = -1;

    int e_loc[8];
    int cnt[NE];
#pragma unroll
    for (int e = 0; e < NE; ++e) cnt[e] = 0;
#pragma unroll
    for (int i = 0; i < 8; ++i) {
        int e = eid[tid * 8 + i];
        e_loc[i] = e;
        cnt[e]++;
    }
#pragma unroll
    for (int e = 0; e < NE; ++e) sc[tid][e] = cnt[e];
    __syncthreads();
    for (int stride = 1; stride < 1024; stride <<= 1) {
        int v[NE];
        if (tid >= stride) {
#pragma unroll
            for (int e = 0; e < NE; ++e) v[e] = sc[tid - stride][e];
        } else {
#pragma unroll
            for (int e = 0; e < NE; ++e) v[e] = 0;
        }
        __syncthreads();
#pragma unroll
        for (int e = 0; e < NE; ++e) sc[tid][e] += v[e];
        __syncthreads();
    }
    int off_[NE];
#pragma unroll
    for (int e = 0; e < NE; ++e) off_[e] = (tid == 0) ? 0 : sc[tid - 1][e];
#pragma unroll
    for (int i = 0; i < 8; ++i) {
        int e = e_loc[i];
        int loc = off_[e]++;
        if (loc < CAP) slot_token[e * CAP + loc] = tid * 8 + i;
    }
}

// ---------------- f32 [E][K][N] -> bf16 [E][N][K] convert+transpose ----------------
template<int K, int N>
__global__ __launch_bounds__(256) void convT_kernel(
    const float* __restrict__ W, unsigned short* __restrict__ WT)
{
    __shared__ unsigned short tile[64][66];
    int e = blockIdx.z;
    int k0 = blockIdx.y * 64, n0 = blockIdx.x * 64;
    const float* Wp = W + (size_t)e * K * N;
    unsigned short* WTp = WT + (size_t)e * K * N;
    int tid = threadIdx.x;
    int cn = (tid & 15) * 4;
    int rk = tid >> 4;
#pragma unroll
    for (int i = 0; i < 4; ++i) {
        int k = rk + i * 16;
        float4 v = *(const float4*)(Wp + (size_t)(k0 + k) * N + n0 + cn);
        tile[cn + 0][k] = f2bf(v.x);
        tile[cn + 1][k] = f2bf(v.y);
        tile[cn + 2][k] = f2bf(v.z);
        tile[cn + 3][k] = f2bf(v.w);
    }
    __syncthreads();
    int ck = (tid & 15) * 4;
    int rn = tid >> 4;
#pragma unroll
    for (int i = 0; i < 4; ++i) {
        int n = rn + i * 16;
        ushort4 o;
        o.x = tile[n][ck + 0]; o.y = tile[n][ck + 1];
        o.z = tile[n][ck + 2]; o.w = tile[n][ck + 3];
        *(ushort4*)(WTp + (size_t)(n0 + n) * K + k0 + ck) = o;
    }
}

// ---------------- gather dispatched tokens into bf16 [E*C][m] ----------------
__global__ __launch_bounds__(256) void gather_kernel(
    const float* __restrict__ x, const int* __restrict__ slot_token,
    unsigned short* __restrict__ Xd)
{
    int slot = blockIdx.x;
    int t = slot_token[slot];
    int c4 = threadIdx.x * 4;
    ushort4 o;
    if (t >= 0) {
        float4 v = *(const float4*)(x + (size_t)t * DM + c4);
        o.x = f2bf(v.x); o.y = f2bf(v.y); o.z = f2bf(v.z); o.w = f2bf(v.w);
    } else {
        o.x = 0; o.y = 0; o.z = 0; o.w = 0;
    }
    *(ushort4*)(Xd + (size_t)slot * DM + c4) = o;
}

// ---------------- m97-style bf16 GEMM core: 128x128 tile, BK=32 ----------------
// A: [128 rows][K] k-contig; B: [128 cols][K] k-contig (i.e. B^T). acc 4x4 f32x4.
template<int K>
__device__ __forceinline__ void gemm_core(
    const unsigned short* __restrict__ Ab, const unsigned short* __restrict__ Bb,
    unsigned short* As, unsigned short* Bs, f32x4 acc[4][4])
{
    int tid = threadIdx.x;
    int wave = tid >> 6, lane = tid & 63;
    int wr = (wave >> 1) * 64;
    int wc = (wave & 1) * 64;
#pragma unroll
    for (int i = 0; i < 4; ++i)
#pragma unroll
        for (int j = 0; j < 4; ++j) acc[i][j] = (f32x4){0.f, 0.f, 0.f, 0.f};

    int srow = (lane >> 2);          // 0..15 within 16-row group
    int scol = (lane & 3) * 8;       // element offset in BK window

    for (int kt = 0; kt < K; kt += 32) {
#pragma unroll
        for (int i = 0; i < 2; ++i) {
            int q = wave * 2 + i;                 // 0..7 : 16-row group
            int row = q * 16 + srow;
            const unsigned short* ga = Ab + (size_t)row * K + kt + scol;
            const unsigned short* gb = Bb + (size_t)row * K + kt + scol;
            async_cp16(ga, As + q * 512);
            async_cp16(gb, Bs + q * 512);
        }
        __syncthreads();
        bf16x8 af[4], bfr[4];
#pragma unroll
        for (int i = 0; i < 4; ++i) {
            int r = wr + i * 16 + (lane & 15);
            af[i] = *(const bf16x8*)(As + r * 32 + (lane >> 4) * 8);
        }
#pragma unroll
        for (int j = 0; j < 4; ++j) {
            int c = wc + j * 16 + (lane & 15);
            bfr[j] = *(const bf16x8*)(Bs + c * 32 + (lane >> 4) * 8);
        }
#pragma unroll
        for (int i = 0; i < 4; ++i)
#pragma unroll
            for (int j = 0; j < 4; ++j)
                acc[i][j] = __builtin_amdgcn_mfma_f32_16x16x32_bf16(af[i], bfr[j], acc[i][j], 0, 0, 0);
        __syncthreads();
    }
}

// GEMM1: H[e] = relu(Xd[e] @ W1[e]) -> bf16.  M=CAP, N=NF, K=DM.
__global__ __launch_bounds__(256, 2) void gemm1_kernel(
    const unsigned short* __restrict__ Xd, const unsigned short* __restrict__ W1T,
    unsigned short* __restrict__ H)
{
    __shared__ unsigned short As[128 * 32];
    __shared__ unsigned short Bs[128 * 32];
    int e = blockIdx.z;
    const unsigned short* Ab = Xd + ((size_t)e * CAP + blockIdx.y * 128) * DM;
    const unsigned short* Bb = W1T + ((size_t)e * NF + blockIdx.x * 128) * DM;
    f32x4 acc[4][4];
    gemm_core<DM>(Ab, Bb, As, Bs, acc);

    int tid = threadIdx.x, wave = tid >> 6, lane = tid & 63;
    int wr = (wave >> 1) * 64, wc = (wave & 1) * 64;
    size_t Hbase = ((size_t)e * CAP + blockIdx.y * 128) * NF + blockIdx.x * 128;
#pragma unroll
    for (int i = 0; i < 4; ++i) {
#pragma unroll
        for (int j = 0; j < 4; ++j) {
            int col = wc + j * 16 + (lane & 15);
#pragma unroll
            for (int f = 0; f < 4; ++f) {
                int row = wr + i * 16 + (lane >> 4) * 4 + f;
                float v = acc[i][j][f];
                v = v > 0.f ? v : 0.f;
                H[Hbase + (size_t)row * NF + col] = f2bf(v);
            }
        }
    }
}

// GEMM2: EO[e] = H[e] @ W2[e]; scatter out[token] = gate * EO.  M=CAP, N=DM, K=NF.
__global__ __launch_bounds__(256, 2) void gemm2_kernel(
    const unsigned short* __restrict__ H, const unsigned short* __restrict__ W2T,
    const int* __restrict__ slot_token, const float* __restrict__ gatev,
    float* __restrict__ out)
{
    __shared__ unsigned short As[128 * 32];
    __shared__ unsigned short Bs[128 * 32];
    int e = blockIdx.z;
    const unsigned short* Ab = H + ((size_t)e * CAP + blockIdx.y * 128) * NF;
    const unsigned short* Bb = W2T + ((size_t)e * DM + blockIdx.x * 128) * NF;
    f32x4 acc[4][4];
    gemm_core<NF>(Ab, Bb, As, Bs, acc);

    int tid = threadIdx.x, wave = tid >> 6, lane = tid & 63;
    int wr = (wave >> 1) * 64, wc = (wave & 1) * 64;
    int slot0 = e * CAP + blockIdx.y * 128;
#pragma unroll
    for (int i = 0; i < 4; ++i) {
        int rbase = wr + i * 16 + (lane >> 4) * 4;
#pragma unroll
        for (int f = 0; f < 4; ++f) {
            int row = rbase + f;
            int t = slot_token[slot0 + row];
            if (t >= 0) {
                float g = gatev[t];
#pragma unroll
                for (int j = 0; j < 4; ++j) {
                    int col = blockIdx.x * 128 + wc + j * 16 + (lane & 15);
                    out[(size_t)t * DM + col] = acc[i][j][f] * g;
                }
            }
        }
    }
}

extern "C" void kernel_launch(void* const* d_in, const int* in_sizes, int n_in,
                              void* d_out, int out_size, void* d_ws, size_t ws_size,
                              hipStream_t stream)
{
    const float* x  = (const float*)d_in[0];
    const float* wg = (const float*)d_in[1];
    const float* w1 = (const float*)d_in[2];
    const float* w2 = (const float*)d_in[3];
    float* out = (float*)d_out;

    char* ws = (char*)d_ws;
    size_t o = 0;
    auto nxt = [&](size_t b) { size_t r = o; o += (b + 255) & ~(size_t)255; return r; };
    int*   eid        = (int*)  (ws + nxt((size_t)NTOK * 4));
    float* gatev      = (float*)(ws + nxt((size_t)NTOK * 4));
    int*   slot_token = (int*)  (ws + nxt((size_t)NTOK * 4));
    unsigned short* Xd = (unsigned short*)(ws + nxt((size_t)NTOK * DM * 2));
    unsigned short* WT = (unsigned short*)(ws + nxt((size_t)NE * NF * DM * 2)); // W1T then W2T (aliased)
    unsigned short* Hb = (unsigned short*)(ws + nxt((size_t)NE * CAP * NF * 2));

    gate_kernel<<<NTOK / 4, 256, 0, stream>>>(x, wg, eid, gatev);
    scan_kernel<<<1, 1024, 0, stream>>>(eid, slot_token);
    convT_kernel<DM, NF><<<dim3(NF / 64, DM / 64, NE), 256, 0, stream>>>(w1, WT);
    gather_kernel<<<NTOK, 256, 0, stream>>>(x, slot_token, Xd);
    gemm1_kernel<<<dim3(NF / 128, CAP / 128, NE), 256, 0, stream>>>(Xd, WT, Hb);
    convT_kernel<NF, DM><<<dim3(DM / 64, NF / 64, NE), 256, 0, stream>>>(w2, WT);
    hipMemsetAsync(d_out, 0, (size_t)out_size * sizeof(float), stream);
    gemm2_kernel<<<dim3(DM / 128, CAP / 128, NE), 256, 0, stream>>>(Hb, WT, slot_token, gatev, out);
}

// Round 2
// 552.181 us; speedup vs baseline: 1.0114x; 1.0114x over previous
//
#include <hip/hip_runtime.h>
#include <hip/hip_bf16.h>

// MoE top-1 (GShard) for MI355X.
// S=8192 tokens, m=1024, E=8, ffn=4096, C=1024.
// R2: gemm2 retiled 128x64/BK=64 (4 blocks/CU), gemm1 LDS-transpose epilogue,
//     convT 16B writes, wave-shuffle scan, float4 gate.

#define NTOK 8192
#define DM   1024
#define NE   8
#define NF   4096
#define CAP  1024

typedef __bf16 bf16x8 __attribute__((ext_vector_type(8)));
typedef float  f32x4  __attribute__((ext_vector_type(4)));
typedef unsigned short us8v __attribute__((ext_vector_type(8)));

__device__ __forceinline__ unsigned short f2bf(float f) {
    union { float f; unsigned int u; } v; v.f = f;
    unsigned int u = v.u;
    return (unsigned short)((u + 0x7FFFu + ((u >> 16) & 1u)) >> 16); // RNE
}

__device__ __forceinline__ void async_cp16(const unsigned short* g, unsigned short* l) {
    __builtin_amdgcn_global_load_lds(
        (const __attribute__((address_space(1))) void*)g,
        (__attribute__((address_space(3))) void*)l, 16, 0, 0);
}

// ---------------- gating: one wave per token ----------------
__global__ __launch_bounds__(256) void gate_kernel(
    const float* __restrict__ x, const float* __restrict__ wg,
    int* __restrict__ eid, float* __restrict__ gatev)
{
    int wave = threadIdx.x >> 6;
    int lane = threadIdx.x & 63;
    int t = blockIdx.x * 4 + wave;
    const float4* xr4 = (const float4*)(x + (size_t)t * DM);
    float acc[NE];
#pragma unroll
    for (int e = 0; e < NE; ++e) acc[e] = 0.f;
#pragma unroll
    for (int it = 0; it < 4; ++it) {
        int k4 = lane + it * 64;
        float4 xv = xr4[k4];
        float xc[4] = {xv.x, xv.y, xv.z, xv.w};
#pragma unroll
        for (int c = 0; c < 4; ++c) {
            const float4* wr = (const float4*)(wg + (size_t)(k4 * 4 + c) * NE);
            float4 w0 = wr[0], w1 = wr[1];
            acc[0] += xc[c] * w0.x; acc[1] += xc[c] * w0.y;
            acc[2] += xc[c] * w0.z; acc[3] += xc[c] * w0.w;
            acc[4] += xc[c] * w1.x; acc[5] += xc[c] * w1.y;
            acc[6] += xc[c] * w1.z; acc[7] += xc[c] * w1.w;
        }
    }
#pragma unroll
    for (int off = 32; off >= 1; off >>= 1) {
#pragma unroll
        for (int e = 0; e < NE; ++e) acc[e] += __shfl_xor(acc[e], off, 64);
    }
    if (lane == 0) {
        int best = 0; float bm = acc[0];
#pragma unroll
        for (int e = 1; e < NE; ++e) if (acc[e] > bm) { bm = acc[e]; best = e; } // first-max like jnp.argmax
        float ssum = 0.f;
#pragma unroll
        for (int e = 0; e < NE; ++e) ssum += __expf(acc[e] - bm);
        eid[t] = best;
        gatev[t] = 1.0f / ssum;  // softmax prob of argmax expert
    }
}

// ---------------- ordered per-expert cumsum, wave-shuffle scan ----------------
__global__ __launch_bounds__(1024) void scan_kernel(
    const int* __restrict__ eid, int* __restrict__ slot_token)
{
    __shared__ int wtot[16][NE];
    int tid = threadIdx.x;
    int lane = tid & 63, wv = tid >> 6;
#pragma unroll
    for (int i = 0; i < 8; ++i) slot_token[tid + i * 1024] = -1;

    int el[8];
    int cnt[NE];
#pragma unroll
    for (int e = 0; e < NE; ++e) cnt[e] = 0;
#pragma unroll
    for (int i = 0; i < 8; ++i) {
        int e = eid[tid * 8 + i];
        el[i] = e;
        cnt[e]++;
    }
    int incl[NE];
#pragma unroll
    for (int e = 0; e < NE; ++e) incl[e] = cnt[e];
#pragma unroll
    for (int off = 1; off <= 32; off <<= 1) {
#pragma unroll
        for (int e = 0; e < NE; ++e) {
            int v = __shfl_up(incl[e], off, 64);
            if (lane >= off) incl[e] += v;
        }
    }
    if (lane == 63) {
#pragma unroll
        for (int e = 0; e < NE; ++e) wtot[wv][e] = incl[e];
    }
    __syncthreads();
    int base[NE];
#pragma unroll
    for (int e = 0; e < NE; ++e) {
        int s = 0;
        for (int w = 0; w < 16; ++w) s += (w < wv) ? wtot[w][e] : 0;
        base[e] = s + incl[e] - cnt[e];   // exclusive prefix for this thread
    }
#pragma unroll
    for (int i = 0; i < 8; ++i) {
        int e = el[i];
        int loc = base[e]++;
        if (loc < CAP) slot_token[e * CAP + loc] = tid * 8 + i;
    }
}

// ---------------- f32 [E][K][N] -> bf16 [E][N][K] convert+transpose ----------------
template<int K, int N>
__global__ __launch_bounds__(256) void convT_kernel(
    const float* __restrict__ W, unsigned short* __restrict__ WT)
{
    __shared__ unsigned short tile[64][72];
    int e = blockIdx.z;
    int k0 = blockIdx.y * 64, n0 = blockIdx.x * 64;
    const float* Wp = W + (size_t)e * K * N;
    unsigned short* WTp = WT + (size_t)e * K * N;
    int tid = threadIdx.x;
    int cn = (tid & 15) * 4;
    int rk = tid >> 4;
#pragma unroll
    for (int i = 0; i < 4; ++i) {
        int k = rk + i * 16;
        float4 v = *(const float4*)(Wp + (size_t)(k0 + k) * N + n0 + cn);
        tile[cn + 0][k] = f2bf(v.x);
        tile[cn + 1][k] = f2bf(v.y);
        tile[cn + 2][k] = f2bf(v.z);
        tile[cn + 3][k] = f2bf(v.w);
    }
    __syncthreads();
    int ck = (tid & 7) * 8;
    int rn = tid >> 3;
#pragma unroll
    for (int i = 0; i < 2; ++i) {
        int n = rn + i * 32;
        us8v o;
#pragma unroll
        for (int c = 0; c < 8; ++c) o[c] = tile[n][ck + c];
        *(us8v*)(WTp + (size_t)(n0 + n) * K + k0 + ck) = o;
    }
}

// ---------------- gather dispatched tokens into bf16 [E*C][m] ----------------
__global__ __launch_bounds__(256) void gather_kernel(
    const float* __restrict__ x, const int* __restrict__ slot_token,
    unsigned short* __restrict__ Xd)
{
    int tid = threadIdx.x;
    int local = tid & 127;
    int slot = blockIdx.x * 2 + (tid >> 7);
    int t = slot_token[slot];
    int c = local * 8;
    us8v o;
    if (t >= 0) {
        const float4* p = (const float4*)(x + (size_t)t * DM + c);
        float4 v0 = p[0], v1 = p[1];
        o[0] = f2bf(v0.x); o[1] = f2bf(v0.y); o[2] = f2bf(v0.z); o[3] = f2bf(v0.w);
        o[4] = f2bf(v1.x); o[5] = f2bf(v1.y); o[6] = f2bf(v1.z); o[7] = f2bf(v1.w);
    } else {
#pragma unroll
        for (int c8 = 0; c8 < 8; ++c8) o[c8] = 0;
    }
    *(us8v*)(Xd + (size_t)slot * DM + c) = o;
}

// ---------------- m97-style bf16 GEMM core: 128x128 tile, BK=32 ----------------
template<int K>
__device__ __forceinline__ void gemm_core(
    const unsigned short* __restrict__ Ab, const unsigned short* __restrict__ Bb,
    unsigned short* As, unsigned short* Bs, f32x4 acc[4][4])
{
    int tid = threadIdx.x;
    int wave = tid >> 6, lane = tid & 63;
    int wr = (wave >> 1) * 64;
    int wc = (wave & 1) * 64;
#pragma unroll
    for (int i = 0; i < 4; ++i)
#pragma unroll
        for (int j = 0; j < 4; ++j) acc[i][j] = (f32x4){0.f, 0.f, 0.f, 0.f};

    int srow = (lane >> 2);
    int scol = (lane & 3) * 8;

    for (int kt = 0; kt < K; kt += 32) {
#pragma unroll
        for (int i = 0; i < 2; ++i) {
            int q = wave * 2 + i;
            int row = q * 16 + srow;
            async_cp16(Ab + (size_t)row * K + kt + scol, As + q * 512);
            async_cp16(Bb + (size_t)row * K + kt + scol, Bs + q * 512);
        }
        __syncthreads();
        bf16x8 af[4], bfr[4];
#pragma unroll
        for (int i = 0; i < 4; ++i) {
            int r = wr + i * 16 + (lane & 15);
            af[i] = *(const bf16x8*)(As + r * 32 + (lane >> 4) * 8);
        }
#pragma unroll
        for (int j = 0; j < 4; ++j) {
            int c = wc + j * 16 + (lane & 15);
            bfr[j] = *(const bf16x8*)(Bs + c * 32 + (lane >> 4) * 8);
        }
#pragma unroll
        for (int i = 0; i < 4; ++i)
#pragma unroll
            for (int j = 0; j < 4; ++j)
                acc[i][j] = __builtin_amdgcn_mfma_f32_16x16x32_bf16(af[i], bfr[j], acc[i][j], 0, 0, 0);
        __syncthreads();
    }
}

// GEMM1: H[e] = relu(Xd[e] @ W1[e]) -> bf16, LDS-transpose epilogue w/ 16B stores.
__global__ __launch_bounds__(256, 2) void gemm1_kernel(
    const unsigned short* __restrict__ Xd, const unsigned short* __restrict__ W1T,
    unsigned short* __restrict__ H)
{
    __shared__ unsigned short smem[8192];   // As(4096) + Bs(4096); reused as epilogue buf
    unsigned short* As = smem;
    unsigned short* Bs = smem + 4096;
    int e = blockIdx.z;
    const unsigned short* Ab = Xd + ((size_t)e * CAP + blockIdx.y * 128) * DM;
    const unsigned short* Bb = W1T + ((size_t)e * NF + blockIdx.x * 128) * DM;
    f32x4 acc[4][4];
    gemm_core<DM>(Ab, Bb, As, Bs, acc);

    int tid = threadIdx.x, wave = tid >> 6, lane = tid & 63;
    int wc = (wave & 1) * 64;
    size_t Hrow0 = ((size_t)e * CAP + blockIdx.y * 128) * NF + blockIdx.x * 128;
    unsigned short* buf = smem;  // 64 rows x 128 cols bf16 = 16KB
#pragma unroll
    for (int p = 0; p < 2; ++p) {
        if ((wave >> 1) == p) {
#pragma unroll
            for (int i = 0; i < 4; ++i) {
#pragma unroll
                for (int j = 0; j < 4; ++j) {
                    int col = wc + j * 16 + (lane & 15);
#pragma unroll
                    for (int f = 0; f < 4; ++f) {
                        int lr = i * 16 + (lane >> 4) * 4 + f;
                        float v = acc[i][j][f];
                        v = v > 0.f ? v : 0.f;
                        buf[lr * 128 + col] = f2bf(v);
                    }
                }
            }
        }
        __syncthreads();
#pragma unroll
        for (int v = 0; v < 4; ++v) {
            int sidx = tid + v * 256;
            int r = sidx >> 4, seg = sidx & 15;
            us8v o = *(const us8v*)(buf + r * 128 + seg * 8);
            *(us8v*)(H + Hrow0 + (size_t)(p * 64 + r) * NF + seg * 8) = o;
        }
        __syncthreads();
    }
}

// GEMM2: EO[e] = H[e] @ W2[e]; 128x64 tile, BK=64, gate-scale + scatter.
__global__ __launch_bounds__(256, 4) void gemm2_kernel(
    const unsigned short* __restrict__ H, const unsigned short* __restrict__ W2T,
    const int* __restrict__ slot_token, const float* __restrict__ gatev,
    float* __restrict__ out)
{
    __shared__ unsigned short As[128 * 64];   // 16KB: 128 slot-rows x 64 k
    __shared__ unsigned short Bs[64 * 64];    // 8KB:  64 col-rows  x 64 k
    int e = blockIdx.z;
    const unsigned short* Ab = H + ((size_t)e * CAP + blockIdx.y * 128) * NF;
    const unsigned short* Bb = W2T + ((size_t)e * DM + blockIdx.x * 64) * NF;

    int tid = threadIdx.x, wave = tid >> 6, lane = tid & 63;
    int wr = (wave >> 1) * 64;     // 64-row half
    int wc = (wave & 1) * 32;      // 32-col half
    f32x4 acc[4][2];
#pragma unroll
    for (int i = 0; i < 4; ++i)
#pragma unroll
        for (int j = 0; j < 2; ++j) acc[i][j] = (f32x4){0.f, 0.f, 0.f, 0.f};

    int srow = lane >> 3;            // 0..7 within 8-row chunk
    int scol = (lane & 7) * 8;       // element offset in BK=64 window

    for (int kt = 0; kt < NF; kt += 64) {
#pragma unroll
        for (int i = 0; i < 4; ++i) {
            int q = wave * 4 + i;                 // 16 A-chunks of 8 rows
            int row = q * 8 + srow;
            async_cp16(Ab + (size_t)row * NF + kt + scol, As + q * 512);
        }
#pragma unroll
        for (int i = 0; i < 2; ++i) {
            int q = wave * 2 + i;                 // 8 B-chunks of 8 rows
            int row = q * 8 + srow;
            async_cp16(Bb + (size_t)row * NF + kt + scol, Bs + q * 512);
        }
        __syncthreads();
#pragma unroll
        for (int h = 0; h < 2; ++h) {
            bf16x8 af[4], bfr[2];
#pragma unroll
            for (int i = 0; i < 4; ++i) {
                int r = wr + i * 16 + (lane & 15);
                af[i] = *(const bf16x8*)(As + r * 64 + h * 32 + (lane >> 4) * 8);
            }
#pragma unroll
            for (int j = 0; j < 2; ++j) {
                int c = wc + j * 16 + (lane & 15);
                bfr[j] = *(const bf16x8*)(Bs + c * 64 + h * 32 + (lane >> 4) * 8);
            }
#pragma unroll
            for (int i = 0; i < 4; ++i)
#pragma unroll
                for (int j = 0; j < 2; ++j)
                    acc[i][j] = __builtin_amdgcn_mfma_f32_16x16x32_bf16(af[i], bfr[j], acc[i][j], 0, 0, 0);
        }
        __syncthreads();
    }

    int slot0 = e * CAP + blockIdx.y * 128;
#pragma unroll
    for (int i = 0; i < 4; ++i) {
        int rbase = wr + i * 16 + (lane >> 4) * 4;
#pragma unroll
        for (int f = 0; f < 4; ++f) {
            int row = rbase + f;
            int t = slot_token[slot0 + row];
            if (t >= 0) {
                float g = gatev[t];
#pragma unroll
                for (int j = 0; j < 2; ++j) {
                    int col = blockIdx.x * 64 + wc + j * 16 + (lane & 15);
                    out[(size_t)t * DM + col] = acc[i][j][f] * g;
                }
            }
        }
    }
}

extern "C" void kernel_launch(void* const* d_in, const int* in_sizes, int n_in,
                              void* d_out, int out_size, void* d_ws, size_t ws_size,
                              hipStream_t stream)
{
    const float* x  = (const float*)d_in[0];
    const float* wg = (const float*)d_in[1];
    const float* w1 = (const float*)d_in[2];
    const float* w2 = (const float*)d_in[3];
    float* out = (float*)d_out;

    char* ws = (char*)d_ws;
    size_t o = 0;
    auto nxt = [&](size_t b) { size_t r = o; o += (b + 255) & ~(size_t)255; return r; };
    int*   eid        = (int*)  (ws + nxt((size_t)NTOK * 4));
    float* gatev      = (float*)(ws + nxt((size_t)NTOK * 4));
    int*   slot_token = (int*)  (ws + nxt((size_t)NTOK * 4));
    unsigned short* Xd = (unsigned short*)(ws + nxt((size_t)NTOK * DM * 2));
    unsigned short* WT = (unsigned short*)(ws + nxt((size_t)NE * NF * DM * 2)); // W1T then W2T (aliased)
    unsigned short* Hb = (unsigned short*)(ws + nxt((size_t)NE * CAP * NF * 2));

    gate_kernel<<<NTOK / 4, 256, 0, stream>>>(x, wg, eid, gatev);
    scan_kernel<<<1, 1024, 0, stream>>>(eid, slot_token);
    convT_kernel<DM, NF><<<dim3(NF / 64, DM / 64, NE), 256, 0, stream>>>(w1, WT);
    gather_kernel<<<NTOK / 2, 256, 0, stream>>>(x, slot_token, Xd);
    gemm1_kernel<<<dim3(NF / 128, CAP / 128, NE), 256, 0, stream>>>(Xd, WT, Hb);
    convT_kernel<NF, DM><<<dim3(DM / 64, NF / 64, NE), 256, 0, stream>>>(w2, WT);
    hipMemsetAsync(d_out, 0, (size_t)out_size * sizeof(float), stream);
    gemm2_kernel<<<dim3(DM / 64, CAP / 128, NE), 256, 0, stream>>>(Hb, WT, slot_token, gatev, out);
}